// Round 22
// baseline (388.436 us; speedup 1.0000x reference)
//
#include <hip/hip_runtime.h>
#include <hip/hip_bf16.h>
#include <stdint.h>
#include <math.h>

#define T_TOK 1024
#define H_DIM 2048
#define E_NUM 16
#define I_DIM 1408
#define TOPK  4
#define SI_DIM 2816
#define NSLOT (T_TOK * TOPK)

typedef short bf16x8 __attribute__((ext_vector_type(8)));
typedef float f32x4  __attribute__((ext_vector_type(4)));

__device__ __forceinline__ uint32_t fbf(float f) {
  __hip_bfloat16 h = __float2bfloat16(f);
  return (uint32_t)*reinterpret_cast<uint16_t*>(&h);
}
__device__ __forceinline__ float asf(uint32_t u) {
  union { uint32_t u; float f; } c; c.u = u; return c.f;
}

typedef const __attribute__((address_space(1))) char gld_g;
typedef __attribute__((address_space(3))) char gld_l;
__device__ __forceinline__ void gload16(const void* g, void* l) {
  __builtin_amdgcn_global_load_lds((gld_g*)g, (gld_l*)l, 16, 0, 0);
}

// ---------------- router ----------------
__global__ __launch_bounds__(256) void k_router(const float* __restrict__ x,
                                                const float* __restrict__ gw,
                                                int* __restrict__ topk_id,
                                                float* __restrict__ topk_w) {
  int t = blockIdx.x;
  float acc[E_NUM];
#pragma unroll
  for (int e = 0; e < E_NUM; ++e) acc[e] = 0.f;
  for (int h = threadIdx.x; h < H_DIM; h += 256) {
    float xv = x[(long)t * H_DIM + h];
#pragma unroll
    for (int e = 0; e < E_NUM; ++e) acc[e] += xv * gw[e * H_DIM + h];
  }
#pragma unroll
  for (int e = 0; e < E_NUM; ++e) {
#pragma unroll
    for (int off = 32; off; off >>= 1) acc[e] += __shfl_down(acc[e], off);
  }
  __shared__ float part[4][E_NUM];
  int wid = threadIdx.x >> 6, lane = threadIdx.x & 63;
  if (lane == 0) {
#pragma unroll
    for (int e = 0; e < E_NUM; ++e) part[wid][e] = acc[e];
  }
  __syncthreads();
  if (threadIdx.x == 0) {
    float lg[E_NUM], p[E_NUM];
    float m = -1e30f;
    for (int e = 0; e < E_NUM; ++e) {
      lg[e] = part[0][e] + part[1][e] + part[2][e] + part[3][e];
      m = fmaxf(m, lg[e]);
    }
    float s = 0.f;
    for (int e = 0; e < E_NUM; ++e) { p[e] = expf(lg[e] - m); s += p[e]; }
    float inv = 1.f / s;
    for (int e = 0; e < E_NUM; ++e) p[e] *= inv;
    float gs[4];
    for (int g = 0; g < 4; ++g) {
      float mg = p[g * 4];
      for (int i = 1; i < 4; ++i) mg = fmaxf(mg, p[g * 4 + i]);
      gs[g] = mg;
    }
    int g1 = 0;
    for (int g = 1; g < 4; ++g) if (gs[g] > gs[g1]) g1 = g;
    int g2 = -1;
    for (int g = 0; g < 4; ++g) {
      if (g == g1) continue;
      if (g2 < 0 || gs[g] > gs[g2]) g2 = g;
    }
    float q[E_NUM];
    for (int e = 0; e < E_NUM; ++e)
      q[e] = ((e >> 2) == g1 || (e >> 2) == g2) ? p[e] : -1e30f;
    int ids[TOPK]; float wv[TOPK]; float wsum = 0.f;
    for (int k = 0; k < TOPK; ++k) {
      int best = 0; float bv = -2e30f;
      for (int e = 0; e < E_NUM; ++e) if (q[e] > bv) { bv = q[e]; best = e; }
      ids[k] = best; wv[k] = p[best]; wsum += p[best]; q[best] = -3e30f;
    }
    float winv = 1.f / wsum;
    for (int k = 0; k < TOPK; ++k) {
      topk_id[t * TOPK + k] = ids[k];
      topk_w[t * TOPK + k] = wv[k] * winv;
    }
  }
}

// ---------------- per-expert counts ----------------
__global__ __launch_bounds__(256) void k_count(const int* __restrict__ topk_id,
                                               int* __restrict__ counts) {
  int e = blockIdx.x, tid = threadIdx.x;
  int c = 0;
  for (int s = tid; s < NSLOT; s += 256) c += (topk_id[s] == e);
#pragma unroll
  for (int off = 32; off; off >>= 1) c += __shfl_down(c, off);
  __shared__ int wsum[4];
  int wid = tid >> 6, lane = tid & 63;
  if (lane == 0) wsum[wid] = c;
  __syncthreads();
  if (tid == 0) counts[e] = wsum[0] + wsum[1] + wsum[2] + wsum[3];
}

// cum granularity = 256 rows (BM=256 blocks)
__global__ void k_offs(const int* __restrict__ counts, int* __restrict__ offs,
                       int* __restrict__ cum) {
  if (threadIdx.x == 0 && blockIdx.x == 0) {
    int s = 0, c = 0;
    cum[0] = 0;
    for (int e = 0; e < E_NUM; ++e) {
      offs[e] = s; s += counts[e];
      c += (counts[e] + 255) >> 8;
      cum[e + 1] = c;
    }
    offs[E_NUM] = s;
  }
}

// ---------------- deterministic compaction ----------------
__global__ __launch_bounds__(256) void k_fill(const int* __restrict__ topk_id,
                                              const int* __restrict__ offs,
                                              int* __restrict__ tok_of_row,
                                              int* __restrict__ row_of_slot) {
  int e = blockIdx.x, tid = threadIdx.x;
  int t0 = tid * 4;
  int match[4]; int cnt = 0;
#pragma unroll
  for (int i = 0; i < 4; ++i) {
    int t = t0 + i; int mk = -1;
#pragma unroll
    for (int k = 0; k < TOPK; ++k) if (topk_id[t * TOPK + k] == e) mk = k;
    match[i] = mk; cnt += (mk >= 0);
  }
  __shared__ int sc[256];
  sc[tid] = cnt; __syncthreads();
  for (int d = 1; d < 256; d <<= 1) {
    int v = sc[tid];
    if (tid >= d) v += sc[tid - d];
    __syncthreads();
    sc[tid] = v;
    __syncthreads();
  }
  int row = offs[e] + sc[tid] - cnt;
#pragma unroll
  for (int i = 0; i < 4; ++i) {
    if (match[i] >= 0) {
      tok_of_row[row] = t0 + i;
      row_of_slot[(t0 + i) * TOPK + match[i]] = row;
      ++row;
    }
  }
}

// ---------------- x fp32 -> bf16 ----------------
__global__ __launch_bounds__(256) void k_cvt(const float* __restrict__ in,
                                             uint16_t* __restrict__ out) {
  int i = (blockIdx.x * 256 + threadIdx.x) * 4;
  float4 v = *(const float4*)(in + i);
  uint2 p;
  p.x = fbf(v.x) | (fbf(v.y) << 16);
  p.y = fbf(v.z) | (fbf(v.w) << 16);
  *(uint2*)(out + i) = p;
}

// ---- 256xBN GEMM, 256 thr, BK=32 — SINGLE barrier per k-step --------------
// MODE 0: C = silu(A@Bg)*(A@Bu) -> bf16, BN=64  (2 B mats)
// MODE 1: C = A@B -> bf16 or f32 (flag),  BN=128
// Change vs the proven 322us kernel: B LDS is DOUBLE-buffered and staged one
// iteration ahead (write B(t+1)->buf^1 while computing t from buf), so the
// per-step sync2 (lgkm+s_barrier) is deleted. The one __syncthreads per step
// orders everything: drains A(t) gloads (vmcnt), publishes the PREVIOUS
// iteration's B ds_writes (lgkmcnt), fences buffer reuse. Two named B reg
// sets (rule #20), loop unrolled x2; nk even for all K (64/44/88).
// LDS 53248B: A dbuf 2x16384; B dbuf 2x10240 @32768.
template <int MODE>
__global__ __launch_bounds__(256, 2) void k_gemm(
    const uint16_t* __restrict__ As, int ldas,
    const float* __restrict__ Bs, int ldbs, int upS,
    void* __restrict__ OutS, int ldoS, int NMs, int NNs, int Ks, int f32S,
    const uint16_t* __restrict__ Ar, int ldar,
    const float* __restrict__ Br, int ldbr, long bstr, int upR,
    void* __restrict__ OutR, int ldoR, int NN1, int K1, int f32R,
    const int* __restrict__ offs, const int* __restrict__ rowlist,
    const int* __restrict__ cum) {
  constexpr int BN = (MODE == 0) ? 64 : 128;
  constexpr int NI = (MODE == 0) ? 2 : 4;
  constexpr int BB = 32768;              // B LDS base
  constexpr int BBUF = 10240;            // B buffer stride (dbuf)
  constexpr int BMS = 5120;              // B mat stride within buffer (MODE0)
  __shared__ char smem[53248];           // A: 2x16384; B: 2x10240

  const int S = NMs * NNs;
  const int NBw = S + cum[E_NUM] * NN1;
  int f = blockIdx.x;
  if (f >= NBw) return;
  int q = NBw >> 3, r = NBw & 7;
  int xcd = f & 7, o = f >> 3;
  int f2 = (xcd < r ? xcd * (q + 1) : r * (q + 1) + (xcd - r) * q) + o;

  const uint16_t* A; const float* Bp; void* Outp; const int* rl;
  int lda, ldb, up, ldo, K, m0, n0, row_end, isf32;
  if (f2 < S) {
    int mb = f2 % NMs, nb = f2 / NMs;
    A = As; lda = ldas; Bp = Bs; ldb = ldbs; up = upS;
    Outp = OutS; ldo = ldoS; K = Ks; isf32 = f32S; rl = nullptr;
    m0 = mb * 256; row_end = NMs * 256; n0 = nb * BN;
  } else {
    int g = f2 - S;
    int e = 0;
    for (e = 0; e < E_NUM; ++e) if (g < cum[e + 1] * NN1) break;
    if (e == E_NUM) return;
    int nmbe = cum[e + 1] - cum[e];
    int loc = g - cum[e] * NN1;
    int mb = loc % nmbe, nb = loc / nmbe;
    A = Ar; lda = ldar; Bp = Br + (size_t)e * bstr; ldb = ldbr; up = upR;
    Outp = OutR; ldo = ldoR; K = K1; isf32 = f32R; rl = rowlist;
    m0 = offs[e] + mb * 256; row_end = offs[e + 1]; n0 = nb * BN;
  }

  const int tid = threadIdx.x;
  const int wid = tid >> 6, lane = tid & 63;
  const int wm = (wid >> 1) * 64, wn = (wid & 1) * (BN / 2);
  const int lrow = lane & 15, kg = lane >> 4;

  // ---- A staging (identical to proven kernel) ----
  const uint16_t* aSrc[4]; int aDst[4];
#pragma unroll
  for (int p = 0; p < 4; ++p) {
    int rr = wid * 64 + p * 16 + (lane >> 2);
    int grow = m0 + rr;
    grow = grow < row_end - 1 ? grow : row_end - 1;
    int arow = rl ? rl[grow] : grow;
    int sslot = (lane & 3) ^ ((lane >> 3) & 3);
    aSrc[p] = A + (size_t)arow * lda + sslot * 8;
    aDst[p] = wid * 4096 + p * 1024;     // wave-uniform; HW adds lane*16
  }
  auto issueA = [&](int buf) {
#pragma unroll
    for (int p = 0; p < 4; ++p) {
      gload16(aSrc[p], smem + buf * 16384 + aDst[p]);
      aSrc[p] += 32;
    }
  };

  // ---- B staging (offsets now buffer-relative) ----
  int n4, kq, mat;
  if constexpr (MODE == 0) {
    n4 = (tid & 15) * 4; int rest = tid >> 4; kq = rest & 7; mat = rest >> 3;
  } else {
    n4 = (tid & 31) * 4; kq = tid >> 5; mat = 0;
  }
  const int k0 = kq * 4;
  const float* bptr = Bp + (size_t)k0 * ldb + n0 + n4 + (mat ? up : 0);
  const int sq = (kq >> 1) & 3, hf = kq & 1;
  int bw[4];
#pragma unroll
  for (int j = 0; j < 4; ++j) {
    int n = n4 + j;
    bw[j] = mat * BMS + n * 80 + ((sq ^ ((n >> 4) & 3)) << 4) + (hf << 3);
  }

  float4 vA[4], vB[4];                   // two NAMED reg sets (rule #20)
  auto loadB = [&](float4 (&v)[4]) {
#pragma unroll
    for (int i = 0; i < 4; ++i) v[i] = *(const float4*)(bptr + (size_t)i * ldb);
    bptr += (size_t)32 * ldb;
  };
  auto stageB = [&](int buf, const float4 (&v)[4]) {
    char* bb = smem + BB + buf * BBUF;
#pragma unroll
    for (int j = 0; j < 4; ++j) {
      uint2 w;
      w.x = fbf(((const float*)&v[0])[j]) | (fbf(((const float*)&v[1])[j]) << 16);
      w.y = fbf(((const float*)&v[2])[j]) | (fbf(((const float*)&v[3])[j]) << 16);
      *(uint2*)(bb + bw[j]) = w;
    }
  };

  f32x4 zero = {0.f, 0.f, 0.f, 0.f};
  f32x4 accg[2][4][NI];
  f32x4 accu[(MODE == 0) ? 2 : 1][(MODE == 0) ? 4 : 1][(MODE == 0) ? NI : 1];
#pragma unroll
  for (int mt = 0; mt < 2; ++mt)
#pragma unroll
    for (int mi = 0; mi < 4; ++mi)
#pragma unroll
      for (int ni = 0; ni < NI; ++ni) {
        accg[mt][mi][ni] = zero;
        if constexpr (MODE == 0) accu[mt][mi][ni] = zero;
      }

  auto compute = [&](int cur) {
    const char* ab = smem + cur * 16384;
    const char* bb = smem + BB + cur * BBUF;
    const int akx = (kg ^ ((lrow >> 1) & 3)) << 4;
    bf16x8 af[8];
#pragma unroll
    for (int mt = 0; mt < 2; ++mt)
#pragma unroll
      for (int mi = 0; mi < 4; ++mi) {
        int row = mt * 128 + wm + mi * 16 + lrow;
        af[mt * 4 + mi] = *(const bf16x8*)(ab + row * 64 + akx);
      }
#pragma unroll
    for (int ni = 0; ni < NI; ++ni) {
      int n = wn + ni * 16 + lrow;
      int bo = n * 80 + ((kg ^ ((n >> 4) & 3)) << 4);
      bf16x8 bg = *(const bf16x8*)(bb + bo);
#pragma unroll
      for (int mt = 0; mt < 2; ++mt)
#pragma unroll
        for (int mi = 0; mi < 4; ++mi)
          accg[mt][mi][ni] = __builtin_amdgcn_mfma_f32_16x16x32_bf16(
              af[mt * 4 + mi], bg, accg[mt][mi][ni], 0, 0, 0);
      if constexpr (MODE == 0) {
        bf16x8 bu = *(const bf16x8*)(bb + bo + BMS);
#pragma unroll
        for (int mt = 0; mt < 2; ++mt)
#pragma unroll
          for (int mi = 0; mi < 4; ++mi)
            accu[mt][mi][ni] = __builtin_amdgcn_mfma_f32_16x16x32_bf16(
                af[mt * 4 + mi], bu, accu[mt][mi][ni], 0, 0, 0);
      }
    }
  };

  const int nk = K >> 5;                 // 64 / 44 / 88 — all even
  // ---- prologue: B(0) staged to Bbuf0, B(1) regs in flight, A(0)->buf0 ----
  loadB(vA);                             // B(0) regs (oldest vmcnt slots)
  issueA(0);                             // A(0) gloads
  stageB(0, vA);                         // waits B(0) regs only (counted vmcnt)
  loadB(vB);                             // B(1) regs, stays in flight

  for (int kt = 0; kt < nk; kt += 2) {
    // ---- even sub-iter: tile kt (A buf0, B buf0) ----
    __syncthreads();   // drains A(kt) gloads + B-reg loads; publishes B(kt) writes
    if (kt + 1 < nk) { issueA(1); stageB(1, vB); }   // A(kt+1), B(kt+1)->buf1
    if (kt + 2 < nk) loadB(vA);                      // B(kt+2) regs
    compute(0);
    // ---- odd sub-iter: tile kt+1 (A buf1, B buf1) ----
    if (kt + 1 < nk) {
      __syncthreads(); // drains A(kt+1); publishes B(kt+1) writes
      if (kt + 2 < nk) { issueA(0); stageB(0, vA); } // A(kt+2), B(kt+2)->buf0
      if (kt + 3 < nk) loadB(vB);                    // B(kt+3) regs
      compute(1);
    }
  }

  // ---- epilogue: C/D layout col=lane&15, row=(lane>>4)*4+reg ----
#pragma unroll
  for (int mt = 0; mt < 2; ++mt) {
#pragma unroll
    for (int mi = 0; mi < 4; ++mi) {
#pragma unroll
      for (int rr = 0; rr < 4; ++rr) {
        int grow = m0 + mt * 128 + wm + mi * 16 + kg * 4 + rr;
        if (grow >= row_end) continue;
#pragma unroll
        for (int ni = 0; ni < NI; ++ni) {
          int col = n0 + wn + ni * 16 + lrow;
          float g = accg[mt][mi][ni][rr];
          if constexpr (MODE == 0) {
            float u = accu[mt][mi][ni][rr];
            float a = g / (1.f + __expf(-g)) * u;
            ((uint16_t*)Outp)[(size_t)grow * ldo + col] = (uint16_t)fbf(a);
          } else {
            if (isf32)
              ((float*)Outp)[(size_t)grow * ldo + col] = g;
            else
              ((uint16_t*)Outp)[(size_t)grow * ldo + col] = (uint16_t)fbf(g);
          }
        }
      }
    }
  }
}

// ---------------- combine: out = p0 + sum_k w_k * y[slot] -------------------
__global__ __launch_bounds__(256) void k_combine(float* __restrict__ out,
    const uint16_t* __restrict__ y, const int* __restrict__ row_of_slot,
    const float* __restrict__ topk_w, const float* __restrict__ p0) {
  int t = blockIdx.x, tid = threadIdx.x;
  int h = tid * 8;
  size_t off = (size_t)t * H_DIM + h;
  float4 o0 = *(const float4*)(p0 + off);
  float4 o1 = *(const float4*)(p0 + off + 4);
#pragma unroll
  for (int k = 0; k < TOPK; ++k) {
    int row = row_of_slot[t * TOPK + k];
    float wk = topk_w[t * TOPK + k];
    uint4 v = *(const uint4*)(y + (size_t)row * H_DIM + h);
    o0.x += wk * asf(v.x << 16); o0.y += wk * asf(v.x & 0xffff0000u);
    o0.z += wk * asf(v.y << 16); o0.w += wk * asf(v.y & 0xffff0000u);
    o1.x += wk * asf(v.z << 16); o1.y += wk * asf(v.z & 0xffff0000u);
    o1.z += wk * asf(v.w << 16); o1.w += wk * asf(v.w & 0xffff0000u);
  }
  *(float4*)(out + off) = o0;
  *(float4*)(out + off + 4) = o1;
}

extern "C" void kernel_launch(void* const* d_in, const int* in_sizes, int n_in,
                              void* d_out, int out_size, void* d_ws,
                              size_t ws_size, hipStream_t stream) {
  const float* x   = (const float*)d_in[0];
  const float* gw  = (const float*)d_in[1];
  const float* wgu = (const float*)d_in[2];
  const float* wd  = (const float*)d_in[3];
  const float* sgu = (const float*)d_in[4];
  const float* sd  = (const float*)d_in[5];
  float* out = (float*)d_out;

  char* ws = (char*)d_ws;
  int*   topk_id     = (int*)(ws + 0);
  float* topk_w      = (float*)(ws + 16384);
  int*   counts      = (int*)(ws + 32768);
  int*   offs        = (int*)(ws + 33792);
  int*   cum         = (int*)(ws + 34816);
  int*   tok_of_row  = (int*)(ws + 35840);
  int*   row_of_slot = (int*)(ws + 52224);
  uint16_t* x_bf     = (uint16_t*)(ws + 131072);     //  4.19 MB
  uint16_t* act      = (uint16_t*)(ws + 4325376);    // 11.53 MB
  uint16_t* yslots   = (uint16_t*)(ws + 15859712);   // 16.78 MB
  uint16_t* act_sh   = (uint16_t*)(ws + 32636928);   //  5.77 MB
  bool merged = ws_size >= (size_t)38404096 + 8388608;
  float* p0 = merged ? (float*)(ws + 38404096) : (float*)(ws + 4325376);

  k_router<<<T_TOK, 256, 0, stream>>>(x, gw, topk_id, topk_w);
  k_count<<<E_NUM, 256, 0, stream>>>(topk_id, counts);
  k_offs<<<1, 1, 0, stream>>>(counts, offs, cum);
  k_fill<<<E_NUM, 256, 0, stream>>>(topk_id, offs, tok_of_row, row_of_slot);
  k_cvt<<<(T_TOK * H_DIM) / 1024, 256, 0, stream>>>(x, x_bf);

  // d1: shared gate_up (4x44=176) + routed gate_up (worst-case 32 mb x 22)
  k_gemm<0><<<176 + 32 * 22, 256, 0, stream>>>(
      x_bf, H_DIM, sgu, 2 * SI_DIM, SI_DIM, act_sh, SI_DIM, 4, 44, H_DIM, 0,
      x_bf, H_DIM, wgu, 2 * I_DIM, (long)H_DIM * 2 * I_DIM, I_DIM,
      act, I_DIM, 22, H_DIM, 0,
      offs, tok_of_row, cum);

  if (merged) {
    // d2: shared down (4x16=64, f32 out) + routed down (worst 32 x 16)
    k_gemm<1><<<64 + 32 * 16, 256, 0, stream>>>(
        act_sh, SI_DIM, sd, H_DIM, 0, p0, H_DIM, 4, 16, SI_DIM, 1,
        act, I_DIM, wd, H_DIM, (long)I_DIM * H_DIM, 0,
        yslots, H_DIM, 16, I_DIM, 0,
        offs, nullptr, cum);
  } else {
    // fallback (p0 aliases act): routed down first, then shared down only
    k_gemm<1><<<32 * 16, 256, 0, stream>>>(
        act_sh, SI_DIM, sd, H_DIM, 0, p0, H_DIM, 4, 0, SI_DIM, 1,
        act, I_DIM, wd, H_DIM, (long)I_DIM * H_DIM, 0,
        yslots, H_DIM, 16, I_DIM, 0,
        offs, nullptr, cum);
    k_gemm<1><<<64, 256, 0, stream>>>(
        act_sh, SI_DIM, sd, H_DIM, 0, p0, H_DIM, 4, 16, SI_DIM, 1,
        act, I_DIM, wd, H_DIM, (long)I_DIM * H_DIM, 0,
        yslots, H_DIM, 0, I_DIM, 0,
        offs, nullptr, cum);
  }
  k_combine<<<T_TOK, 256, 0, stream>>>(out, yslots, row_of_slot, topk_w, p0);
}

// Round 23
// 321.431 us; speedup vs baseline: 1.2085x; 1.2085x over previous
//
#include <hip/hip_runtime.h>
#include <hip/hip_bf16.h>
#include <stdint.h>
#include <math.h>

#define T_TOK 1024
#define H_DIM 2048
#define E_NUM 16
#define I_DIM 1408
#define TOPK  4
#define SI_DIM 2816
#define NSLOT (T_TOK * TOPK)

typedef short bf16x8 __attribute__((ext_vector_type(8)));
typedef float f32x4  __attribute__((ext_vector_type(4)));

__device__ __forceinline__ uint32_t fbf(float f) {
  __hip_bfloat16 h = __float2bfloat16(f);
  return (uint32_t)*reinterpret_cast<uint16_t*>(&h);
}
__device__ __forceinline__ float asf(uint32_t u) {
  union { uint32_t u; float f; } c; c.u = u; return c.f;
}

typedef const __attribute__((address_space(1))) char gld_g;
typedef __attribute__((address_space(3))) char gld_l;
__device__ __forceinline__ void gload16(const void* g, void* l) {
  __builtin_amdgcn_global_load_lds((gld_g*)g, (gld_l*)l, 16, 0, 0);
}
// barrier that does NOT drain vmcnt (in-flight prefetches survive)
__device__ __forceinline__ void barrier_lgkm() {
  asm volatile("s_waitcnt lgkmcnt(0)" ::: "memory");
  __builtin_amdgcn_s_barrier();
  __builtin_amdgcn_sched_barrier(0);
}

// ---------------- router ----------------
__global__ __launch_bounds__(256) void k_router(const float* __restrict__ x,
                                                const float* __restrict__ gw,
                                                int* __restrict__ topk_id,
                                                float* __restrict__ topk_w) {
  int t = blockIdx.x;
  float acc[E_NUM];
#pragma unroll
  for (int e = 0; e < E_NUM; ++e) acc[e] = 0.f;
  for (int h = threadIdx.x; h < H_DIM; h += 256) {
    float xv = x[(long)t * H_DIM + h];
#pragma unroll
    for (int e = 0; e < E_NUM; ++e) acc[e] += xv * gw[e * H_DIM + h];
  }
#pragma unroll
  for (int e = 0; e < E_NUM; ++e) {
#pragma unroll
    for (int off = 32; off; off >>= 1) acc[e] += __shfl_down(acc[e], off);
  }
  __shared__ float part[4][E_NUM];
  int wid = threadIdx.x >> 6, lane = threadIdx.x & 63;
  if (lane == 0) {
#pragma unroll
    for (int e = 0; e < E_NUM; ++e) part[wid][e] = acc[e];
  }
  __syncthreads();
  if (threadIdx.x == 0) {
    float lg[E_NUM], p[E_NUM];
    float m = -1e30f;
    for (int e = 0; e < E_NUM; ++e) {
      lg[e] = part[0][e] + part[1][e] + part[2][e] + part[3][e];
      m = fmaxf(m, lg[e]);
    }
    float s = 0.f;
    for (int e = 0; e < E_NUM; ++e) { p[e] = expf(lg[e] - m); s += p[e]; }
    float inv = 1.f / s;
    for (int e = 0; e < E_NUM; ++e) p[e] *= inv;
    float gs[4];
    for (int g = 0; g < 4; ++g) {
      float mg = p[g * 4];
      for (int i = 1; i < 4; ++i) mg = fmaxf(mg, p[g * 4 + i]);
      gs[g] = mg;
    }
    int g1 = 0;
    for (int g = 1; g < 4; ++g) if (gs[g] > gs[g1]) g1 = g;
    int g2 = -1;
    for (int g = 0; g < 4; ++g) {
      if (g == g1) continue;
      if (g2 < 0 || gs[g] > gs[g2]) g2 = g;
    }
    float q[E_NUM];
    for (int e = 0; e < E_NUM; ++e)
      q[e] = ((e >> 2) == g1 || (e >> 2) == g2) ? p[e] : -1e30f;
    int ids[TOPK]; float wv[TOPK]; float wsum = 0.f;
    for (int k = 0; k < TOPK; ++k) {
      int best = 0; float bv = -2e30f;
      for (int e = 0; e < E_NUM; ++e) if (q[e] > bv) { bv = q[e]; best = e; }
      ids[k] = best; wv[k] = p[best]; wsum += p[best]; q[best] = -3e30f;
    }
    float winv = 1.f / wsum;
    for (int k = 0; k < TOPK; ++k) {
      topk_id[t * TOPK + k] = ids[k];
      topk_w[t * TOPK + k] = wv[k] * winv;
    }
  }
}

// ---------------- per-expert counts ----------------
__global__ __launch_bounds__(256) void k_count(const int* __restrict__ topk_id,
                                               int* __restrict__ counts) {
  int e = blockIdx.x, tid = threadIdx.x;
  int c = 0;
  for (int s = tid; s < NSLOT; s += 256) c += (topk_id[s] == e);
#pragma unroll
  for (int off = 32; off; off >>= 1) c += __shfl_down(c, off);
  __shared__ int wsum[4];
  int wid = tid >> 6, lane = tid & 63;
  if (lane == 0) wsum[wid] = c;
  __syncthreads();
  if (tid == 0) counts[e] = wsum[0] + wsum[1] + wsum[2] + wsum[3];
}

// cum granularity = 256 rows (BM=256 blocks)
__global__ void k_offs(const int* __restrict__ counts, int* __restrict__ offs,
                       int* __restrict__ cum) {
  if (threadIdx.x == 0 && blockIdx.x == 0) {
    int s = 0, c = 0;
    cum[0] = 0;
    for (int e = 0; e < E_NUM; ++e) {
      offs[e] = s; s += counts[e];
      c += (counts[e] + 255) >> 8;
      cum[e + 1] = c;
    }
    offs[E_NUM] = s;
  }
}

// ---------------- deterministic compaction ----------------
__global__ __launch_bounds__(256) void k_fill(const int* __restrict__ topk_id,
                                              const int* __restrict__ offs,
                                              int* __restrict__ tok_of_row,
                                              int* __restrict__ row_of_slot) {
  int e = blockIdx.x, tid = threadIdx.x;
  int t0 = tid * 4;
  int match[4]; int cnt = 0;
#pragma unroll
  for (int i = 0; i < 4; ++i) {
    int t = t0 + i; int mk = -1;
#pragma unroll
    for (int k = 0; k < TOPK; ++k) if (topk_id[t * TOPK + k] == e) mk = k;
    match[i] = mk; cnt += (mk >= 0);
  }
  __shared__ int sc[256];
  sc[tid] = cnt; __syncthreads();
  for (int d = 1; d < 256; d <<= 1) {
    int v = sc[tid];
    if (tid >= d) v += sc[tid - d];
    __syncthreads();
    sc[tid] = v;
    __syncthreads();
  }
  int row = offs[e] + sc[tid] - cnt;
#pragma unroll
  for (int i = 0; i < 4; ++i) {
    if (match[i] >= 0) {
      tok_of_row[row] = t0 + i;
      row_of_slot[(t0 + i) * TOPK + match[i]] = row;
      ++row;
    }
  }
}

// ---------------- x fp32 -> bf16 ----------------
__global__ __launch_bounds__(256) void k_cvt(const float* __restrict__ in,
                                             uint16_t* __restrict__ out) {
  int i = (blockIdx.x * 256 + threadIdx.x) * 4;
  float4 v = *(const float4*)(in + i);
  uint2 p;
  p.x = fbf(v.x) | (fbf(v.y) << 16);
  p.y = fbf(v.z) | (fbf(v.w) << 16);
  *(uint2*)(out + i) = p;
}

// ---- 256xBN GEMM (MT=2 m-tiles share staged B), 256 thr, BK=32 ------------
// MODE 0: C = silu(A@Bg)*(A@Bu) -> bf16, BN=64  (2 B mats)
// MODE 1: C = A@B -> bf16 or f32 (flag),  BN=128
// R8's proven schedule, BM=256 so each staged B tile feeds two 128-row
// m-tiles: B (weight) traffic halves, MFMA per barrier-pair doubles.
// LDS 43008B: A dbuf 2x16384 (256 rows x 64B, gload_lds linear dest with
// source slot pre-swizzle (lane>>3)&3; read XOR (lrow>>1)&3 -> 2-way);
// B @32768 single buf [BN][80B rows], slot-XOR (n>>4)&3 both sides.
// Step: sync1(__syncthreads) -> gloadA(t+1)->buf^1 -> stageB(t) ->
//       loadB(t+1 regs) -> barrier_lgkm -> 32 MFMA/wave.
// [Best measured configuration of the session: 322 us, reproduced x6.
//  R22's single-barrier/B-dbuf variant measured 388 us -> reverted.]
template <int MODE>
__global__ __launch_bounds__(256, 2) void k_gemm(
    const uint16_t* __restrict__ As, int ldas,
    const float* __restrict__ Bs, int ldbs, int upS,
    void* __restrict__ OutS, int ldoS, int NMs, int NNs, int Ks, int f32S,
    const uint16_t* __restrict__ Ar, int ldar,
    const float* __restrict__ Br, int ldbr, long bstr, int upR,
    void* __restrict__ OutR, int ldoR, int NN1, int K1, int f32R,
    const int* __restrict__ offs, const int* __restrict__ rowlist,
    const int* __restrict__ cum) {
  constexpr int BN = (MODE == 0) ? 64 : 128;
  constexpr int NI = (MODE == 0) ? 2 : 4;
  constexpr int BB = 32768;              // B LDS base
  constexpr int BMS = 5120;              // B mat stride (MODE0)
  __shared__ char smem[43008];           // A: 2x16384; B: 10240

  const int S = NMs * NNs;
  const int NBw = S + cum[E_NUM] * NN1;
  int f = blockIdx.x;
  if (f >= NBw) return;
  int q = NBw >> 3, r = NBw & 7;
  int xcd = f & 7, o = f >> 3;
  int f2 = (xcd < r ? xcd * (q + 1) : r * (q + 1) + (xcd - r) * q) + o;

  const uint16_t* A; const float* Bp; void* Outp; const int* rl;
  int lda, ldb, up, ldo, K, m0, n0, row_end, isf32;
  if (f2 < S) {
    int mb = f2 % NMs, nb = f2 / NMs;
    A = As; lda = ldas; Bp = Bs; ldb = ldbs; up = upS;
    Outp = OutS; ldo = ldoS; K = Ks; isf32 = f32S; rl = nullptr;
    m0 = mb * 256; row_end = NMs * 256; n0 = nb * BN;
  } else {
    int g = f2 - S;
    int e = 0;
    for (e = 0; e < E_NUM; ++e) if (g < cum[e + 1] * NN1) break;
    if (e == E_NUM) return;
    int nmbe = cum[e + 1] - cum[e];
    int loc = g - cum[e] * NN1;
    int mb = loc % nmbe, nb = loc / nmbe;
    A = Ar; lda = ldar; Bp = Br + (size_t)e * bstr; ldb = ldbr; up = upR;
    Outp = OutR; ldo = ldoR; K = K1; isf32 = f32R; rl = rowlist;
    m0 = offs[e] + mb * 256; row_end = offs[e + 1]; n0 = nb * BN;
  }

  const int tid = threadIdx.x;
  const int wid = tid >> 6, lane = tid & 63;
  const int wm = (wid >> 1) * 64, wn = (wid & 1) * (BN / 2);
  const int lrow = lane & 15, kg = lane >> 4;

  // ---- A staging: 4 gload16 rounds/wave (16 rows x 64B each), 256 rows ----
  // source slot pre-swizzled by (lane>>3)&3 so linear LDS holds
  // LDS[row][s] = global[row][s ^ ((row>>1)&3)]  (row local to round).
  const uint16_t* aSrc[4]; int aDst[4];
#pragma unroll
  for (int p = 0; p < 4; ++p) {
    int rr = wid * 64 + p * 16 + (lane >> 2);
    int grow = m0 + rr;
    grow = grow < row_end - 1 ? grow : row_end - 1;
    int arow = rl ? rl[grow] : grow;
    int sslot = (lane & 3) ^ ((lane >> 3) & 3);
    aSrc[p] = A + (size_t)arow * lda + sslot * 8;
    aDst[p] = wid * 4096 + p * 1024;     // wave-uniform; HW adds lane*16
  }

  // ---- B staging: 4 float4 (4k x 4n fp32) -> cvt -> 4 b64 writes ----------
  int n4, kq, mat;
  if constexpr (MODE == 0) {
    n4 = (tid & 15) * 4; int rest = tid >> 4; kq = rest & 7; mat = rest >> 3;
  } else {
    n4 = (tid & 31) * 4; kq = tid >> 5; mat = 0;
  }
  const int k0 = kq * 4;
  const float* bptr = Bp + (size_t)k0 * ldb + n0 + n4 + (mat ? up : 0);
  const int sq = (kq >> 1) & 3, hf = kq & 1;
  int bw[4];
#pragma unroll
  for (int j = 0; j < 4; ++j) {
    int n = n4 + j;
    bw[j] = BB + mat * BMS + n * 80 + ((sq ^ ((n >> 4) & 3)) << 4) + (hf << 3);
  }

  float4 v[4];
  auto loadB = [&]() {
#pragma unroll
    for (int i = 0; i < 4; ++i) v[i] = *(const float4*)(bptr + (size_t)i * ldb);
    bptr += (size_t)32 * ldb;
  };
  auto stageB = [&]() {
#pragma unroll
    for (int j = 0; j < 4; ++j) {
      uint2 w;
      w.x = fbf(((const float*)&v[0])[j]) | (fbf(((const float*)&v[1])[j]) << 16);
      w.y = fbf(((const float*)&v[2])[j]) | (fbf(((const float*)&v[3])[j]) << 16);
      *(uint2*)(smem + bw[j]) = w;
    }
  };

  f32x4 zero = {0.f, 0.f, 0.f, 0.f};
  f32x4 accg[2][4][NI];
  f32x4 accu[(MODE == 0) ? 2 : 1][(MODE == 0) ? 4 : 1][(MODE == 0) ? NI : 1];
#pragma unroll
  for (int mt = 0; mt < 2; ++mt)
#pragma unroll
    for (int mi = 0; mi < 4; ++mi)
#pragma unroll
      for (int ni = 0; ni < NI; ++ni) {
        accg[mt][mi][ni] = zero;
        if constexpr (MODE == 0) accu[mt][mi][ni] = zero;
      }

  auto compute = [&](int cur) {
    const char* ab = smem + cur * 16384;
    const int akx = (kg ^ ((lrow >> 1) & 3)) << 4;
    bf16x8 af[8];
#pragma unroll
    for (int mt = 0; mt < 2; ++mt)
#pragma unroll
      for (int mi = 0; mi < 4; ++mi) {
        int row = mt * 128 + wm + mi * 16 + lrow;
        af[mt * 4 + mi] = *(const bf16x8*)(ab + row * 64 + akx);
      }
#pragma unroll
    for (int ni = 0; ni < NI; ++ni) {
      int n = wn + ni * 16 + lrow;
      int bo = BB + n * 80 + ((kg ^ ((n >> 4) & 3)) << 4);
      bf16x8 bg = *(const bf16x8*)(smem + bo);
#pragma unroll
      for (int mt = 0; mt < 2; ++mt)
#pragma unroll
        for (int mi = 0; mi < 4; ++mi)
          accg[mt][mi][ni] = __builtin_amdgcn_mfma_f32_16x16x32_bf16(
              af[mt * 4 + mi], bg, accg[mt][mi][ni], 0, 0, 0);
      if constexpr (MODE == 0) {
        bf16x8 bu = *(const bf16x8*)(smem + bo + BMS);
#pragma unroll
        for (int mt = 0; mt < 2; ++mt)
#pragma unroll
          for (int mi = 0; mi < 4; ++mi)
            accu[mt][mi][ni] = __builtin_amdgcn_mfma_f32_16x16x32_bf16(
                af[mt * 4 + mi], bu, accu[mt][mi][ni], 0, 0, 0);
      }
    }
  };

  const int nk = K >> 5;
  // prologue: A(0)->buf0, B(0)->regs
#pragma unroll
  for (int p = 0; p < 4; ++p) { gload16(aSrc[p], smem + aDst[p]); aSrc[p] += 32; }
  loadB();

  for (int kt = 0; kt < nk; ++kt) {
    const int cur = kt & 1;
    __syncthreads();                       // sync1: drains A(kt), B(kt)
    if (kt + 1 < nk) {
#pragma unroll
      for (int p = 0; p < 4; ++p) {        // A(kt+1) -> other buffer
        gload16(aSrc[p], smem + (cur ^ 1) * 16384 + aDst[p]); aSrc[p] += 32;
      }
    }
    stageB();                              // B(kt) regs -> LDS
    if (kt + 1 < nk) loadB();              // B(kt+1) -> regs (in flight)
    barrier_lgkm();                        // sync2: NO vmcnt drain
    compute(cur);
  }

  // ---- epilogue: C/D layout col=lane&15, row=(lane>>4)*4+reg ----
#pragma unroll
  for (int mt = 0; mt < 2; ++mt) {
#pragma unroll
    for (int mi = 0; mi < 4; ++mi) {
#pragma unroll
      for (int rr = 0; rr < 4; ++rr) {
        int grow = m0 + mt * 128 + wm + mi * 16 + kg * 4 + rr;
        if (grow >= row_end) continue;
#pragma unroll
        for (int ni = 0; ni < NI; ++ni) {
          int col = n0 + wn + ni * 16 + lrow;
          float g = accg[mt][mi][ni][rr];
          if constexpr (MODE == 0) {
            float u = accu[mt][mi][ni][rr];
            float a = g / (1.f + __expf(-g)) * u;
            ((uint16_t*)Outp)[(size_t)grow * ldo + col] = (uint16_t)fbf(a);
          } else {
            if (isf32)
              ((float*)Outp)[(size_t)grow * ldo + col] = g;
            else
              ((uint16_t*)Outp)[(size_t)grow * ldo + col] = (uint16_t)fbf(g);
          }
        }
      }
    }
  }
}

// ---------------- combine: out = p0 + sum_k w_k * y[slot] -------------------
__global__ __launch_bounds__(256) void k_combine(float* __restrict__ out,
    const uint16_t* __restrict__ y, const int* __restrict__ row_of_slot,
    const float* __restrict__ topk_w, const float* __restrict__ p0) {
  int t = blockIdx.x, tid = threadIdx.x;
  int h = tid * 8;
  size_t off = (size_t)t * H_DIM + h;
  float4 o0 = *(const float4*)(p0 + off);
  float4 o1 = *(const float4*)(p0 + off + 4);
#pragma unroll
  for (int k = 0; k < TOPK; ++k) {
    int row = row_of_slot[t * TOPK + k];
    float wk = topk_w[t * TOPK + k];
    uint4 v = *(const uint4*)(y + (size_t)row * H_DIM + h);
    o0.x += wk * asf(v.x << 16); o0.y += wk * asf(v.x & 0xffff0000u);
    o0.z += wk * asf(v.y << 16); o0.w += wk * asf(v.y & 0xffff0000u);
    o1.x += wk * asf(v.z << 16); o1.y += wk * asf(v.z & 0xffff0000u);
    o1.z += wk * asf(v.w << 16); o1.w += wk * asf(v.w & 0xffff0000u);
  }
  *(float4*)(out + off) = o0;
  *(float4*)(out + off + 4) = o1;
}

extern "C" void kernel_launch(void* const* d_in, const int* in_sizes, int n_in,
                              void* d_out, int out_size, void* d_ws,
                              size_t ws_size, hipStream_t stream) {
  const float* x   = (const float*)d_in[0];
  const float* gw  = (const float*)d_in[1];
  const float* wgu = (const float*)d_in[2];
  const float* wd  = (const float*)d_in[3];
  const float* sgu = (const float*)d_in[4];
  const float* sd  = (const float*)d_in[5];
  float* out = (float*)d_out;

  char* ws = (char*)d_ws;
  int*   topk_id     = (int*)(ws + 0);
  float* topk_w      = (float*)(ws + 16384);
  int*   counts      = (int*)(ws + 32768);
  int*   offs        = (int*)(ws + 33792);
  int*   cum         = (int*)(ws + 34816);
  int*   tok_of_row  = (int*)(ws + 35840);
  int*   row_of_slot = (int*)(ws + 52224);
  uint16_t* x_bf     = (uint16_t*)(ws + 131072);     //  4.19 MB
  uint16_t* act      = (uint16_t*)(ws + 4325376);    // 11.53 MB
  uint16_t* yslots   = (uint16_t*)(ws + 15859712);   // 16.78 MB
  uint16_t* act_sh   = (uint16_t*)(ws + 32636928);   //  5.77 MB
  bool merged = ws_size >= (size_t)38404096 + 8388608;
  float* p0 = merged ? (float*)(ws + 38404096) : (float*)(ws + 4325376);

  k_router<<<T_TOK, 256, 0, stream>>>(x, gw, topk_id, topk_w);
  k_count<<<E_NUM, 256, 0, stream>>>(topk_id, counts);
  k_offs<<<1, 1, 0, stream>>>(counts, offs, cum);
  k_fill<<<E_NUM, 256, 0, stream>>>(topk_id, offs, tok_of_row, row_of_slot);
  k_cvt<<<(T_TOK * H_DIM) / 1024, 256, 0, stream>>>(x, x_bf);

  // d1: shared gate_up (4x44=176) + routed gate_up (worst-case 32 mb x 22)
  k_gemm<0><<<176 + 32 * 22, 256, 0, stream>>>(
      x_bf, H_DIM, sgu, 2 * SI_DIM, SI_DIM, act_sh, SI_DIM, 4, 44, H_DIM, 0,
      x_bf, H_DIM, wgu, 2 * I_DIM, (long)H_DIM * 2 * I_DIM, I_DIM,
      act, I_DIM, 22, H_DIM, 0,
      offs, tok_of_row, cum);

  if (merged) {
    // d2: shared down (4x16=64, f32 out) + routed down (worst 32 x 16)
    k_gemm<1><<<64 + 32 * 16, 256, 0, stream>>>(
        act_sh, SI_DIM, sd, H_DIM, 0, p0, H_DIM, 4, 16, SI_DIM, 1,
        act, I_DIM, wd, H_DIM, (long)I_DIM * H_DIM, 0,
        yslots, H_DIM, 16, I_DIM, 0,
        offs, nullptr, cum);
  } else {
    // fallback (p0 aliases act): routed down first, then shared down only
    k_gemm<1><<<32 * 16, 256, 0, stream>>>(
        act_sh, SI_DIM, sd, H_DIM, 0, p0, H_DIM, 4, 0, SI_DIM, 1,
        act, I_DIM, wd, H_DIM, (long)I_DIM * H_DIM, 0,
        yslots, H_DIM, 16, I_DIM, 0,
        offs, nullptr, cum);
    k_gemm<1><<<64, 256, 0, stream>>>(
        act_sh, SI_DIM, sd, H_DIM, 0, p0, H_DIM, 4, 16, SI_DIM, 1,
        act, I_DIM, wd, H_DIM, (long)I_DIM * H_DIM, 0,
        yslots, H_DIM, 0, I_DIM, 0,
        offs, nullptr, cum);
  }
  k_combine<<<T_TOK, 256, 0, stream>>>(out, yslots, row_of_slot, topk_w, p0);
}